// Round 11
// baseline (244.754 us; speedup 1.0000x reference)
//
#include <hip/hip_runtime.h>
#include <hip/hip_bf16.h>

typedef __bf16 bf16x8 __attribute__((ext_vector_type(8)));
typedef float f32x4 __attribute__((ext_vector_type(4)));
typedef float f32x8 __attribute__((ext_vector_type(8)));
typedef unsigned short u16x8 __attribute__((ext_vector_type(8)));

#define MFMA16(a, b, c) __builtin_amdgcn_mfma_f32_16x16x32_bf16((a), (b), (c), 0, 0, 0)

static __device__ __forceinline__ unsigned short f2b(float f) {
    union { float f; unsigned int u; } v; v.f = f;
    unsigned int r = v.u + 0x7FFFu + ((v.u >> 16) & 1u);  // RNE
    return (unsigned short)(r >> 16);
}
static __device__ __forceinline__ float b2f(unsigned short s) {
    union { unsigned int u; float f; } v; v.u = ((unsigned int)s) << 16;
    return v.f;
}
static __device__ __forceinline__ bf16x8 cvtv(f32x8 v) {
    bf16x8 r;
    #pragma unroll
    for (int i = 0; i < 8; ++i) r[i] = (__bf16)v[i];
    return r;
}

// ---------------- precompute (bf16, in d_ws) ----------------
// M[d][dp] = sum_e Wq[e][d] * Wk[e][dp]   (B-operand for KM = kw * M^T)
// N[e][d]  = sum_c Wl[e][c] * Wv[c][d]    (B-operand for VN = vw * N^T)
__global__ __launch_bounds__(256) void precompute_mn(
    const float* __restrict__ Wq, const float* __restrict__ Wk,
    const float* __restrict__ Wv, const float* __restrict__ Wl,
    unsigned short* __restrict__ ws)
{
    __shared__ float A[4096], B[4096];
    const int bid = blockIdx.x;          // 8 blocks
    const int which = bid >> 2;          // 0 = M, 1 = N
    const int rq = bid & 3;              // row quad
    const int tid = threadIdx.x;
    for (int i = tid; i < 4096; i += 256) {
        A[i] = which ? Wl[i] : Wq[i];
        B[i] = which ? Wv[i] : Wk[i];
    }
    __syncthreads();
    const int row = rq * 16 + (tid >> 4);
    const int c0  = tid & 15;
    float acc[4] = {0, 0, 0, 0};
    if (which == 0) {        // M[row][col] = sum_e Wq[e][row] * Wk[e][col]
        for (int e = 0; e < 64; ++e) {
            const float s = A[e * 64 + row];
            #pragma unroll
            for (int i = 0; i < 4; ++i) acc[i] += s * B[e * 64 + c0 + 16 * i];
        }
    } else {                 // N[row][col] = sum_c Wl[row][c] * Wv[c][col]
        for (int c = 0; c < 64; ++c) {
            const float s = A[row * 64 + c];
            #pragma unroll
            for (int i = 0; i < 4; ++i) acc[i] += s * B[c * 64 + c0 + 16 * i];
        }
    }
    #pragma unroll
    for (int i = 0; i < 4; ++i)
        ws[which * 4096 + row * 64 + c0 + 16 * i] = f2b(acc[i]);
}

#define PITCH 68
#define NT 6

// Persistent pipelined kernel: 512 blocks x 512 threads (8 waves; two task
// streams h2 of 4 waves). Block g owns the 12 heads of window g: stream h2
// loops NT=6 tasks (task = g*12 + i*2 + h2). Per iteration: KM/VN from
// registers -> barrier -> ISSUE NEXT TASK'S k/v/q LOADS (fly during softmax/
// F/stores) -> S = qw*KM^T -> softmax -> attn -> F = P*VN^T -> out -> barrier.
// mfma 16x16x32 bf16: a/b-frag lane l holds row/col (l&15), k=(l>>4)*8+i;
// D: col=lane&15, row=(lane>>4)*4+reg.
__global__ __launch_bounds__(512, 4) void swca_fused(
    const float* __restrict__ qf,
    const float* __restrict__ kf,
    const float* __restrict__ vf,
    const unsigned short* __restrict__ Mw,   // ws
    const unsigned short* __restrict__ Nw,   // ws + 4096
    const float* __restrict__ pe,
    float* __restrict__ out,
    float* __restrict__ attn)
{
    __shared__ unsigned short kmS[2][64][PITCH];  // KM = kw*M^T  [k][d]
    __shared__ unsigned short vnT[2][64][PITCH];  // VN^T         [e][k]
    __shared__ unsigned short As[2][64][PITCH];   // P (wave-private bands)

    const int bid = blockIdx.x;
    const int g = (bid & 7) * 64 + (bid >> 3);   // XCD-chunked swizzle, 512 blocks

    const int tid = threadIdx.x;
    const int h2  = tid >> 8;                    // task stream
    const int tt   = tid & 255;
    const int wid  = tt >> 6;
    const int lane = tt & 63;
    const int lg   = lane >> 4;   // k-group 0..3
    const int lc   = lane & 15;   // row/col within 16-tile
    const int srow = wid * 16 + lc;
    const int sy = srow >> 3, sx = srow & 7;
    const int r0 = wid * 16 + lg * 4;

    auto ld8 = [](const unsigned short* p) -> bf16x8 {
        return *reinterpret_cast<const bf16x8*>(p);
    };
    auto rbase = [&](int hd, int wn, int bb) -> long {
        const int wy = wn >> 3, wx = wn & 7;
        const int gy = (wy * 8 + sy + 4) & 63;   // +4 roll gather
        const int gx = (wx * 8 + sx + 4) & 63;
        return ((long)bb * 4096 + gy * 64 + gx) * 768 + hd * 64;
    };

    int task = g * 12 + h2;
    int headC = task % 12;
    int winC  = (task / 12) & 63;
    int bC    = (task / 12) >> 6;

    // prologue: task-0 loads
    long rb = rbase(headC, winC, bC);
    f32x8 ck0 = *reinterpret_cast<const f32x8*>(kf + rb + lg * 8);
    f32x8 ck1 = *reinterpret_cast<const f32x8*>(kf + rb + 32 + lg * 8);
    f32x8 cv0 = *reinterpret_cast<const f32x8*>(vf + rb + lg * 8);
    f32x8 cv1 = *reinterpret_cast<const f32x8*>(vf + rb + 32 + lg * 8);
    f32x8 cq0 = *reinterpret_cast<const f32x8*>(qf + rb + lg * 8);
    f32x8 cq1 = *reinterpret_cast<const f32x8*>(qf + rb + 32 + lg * 8);

    for (int it = 0; it < NT; ++it) {
        // ---- KM = kw*M^T, VN = vw*N^T (consume current k/v regs)
        {
            bf16x8 kb0 = cvtv(ck0), kb1 = cvtv(ck1);
            f32x4 acc[4] = {};
            #pragma unroll
            for (int t = 0; t < 4; ++t) {
                acc[t] = MFMA16(kb0, ld8(Mw + (t * 16 + lc) * 64 + lg * 8), acc[t]);
                acc[t] = MFMA16(kb1, ld8(Mw + (t * 16 + lc) * 64 + 32 + lg * 8), acc[t]);
            }
            #pragma unroll
            for (int t = 0; t < 4; ++t)
                #pragma unroll
                for (int j = 0; j < 4; ++j)
                    kmS[h2][wid * 16 + lg * 4 + j][t * 16 + lc] = f2b(acc[t][j]);
        }
        {
            bf16x8 vb0 = cvtv(cv0), vb1 = cvtv(cv1);
            f32x4 acc[4] = {};
            #pragma unroll
            for (int t = 0; t < 4; ++t) {
                acc[t] = MFMA16(vb0, ld8(Nw + (t * 16 + lc) * 64 + lg * 8), acc[t]);
                acc[t] = MFMA16(vb1, ld8(Nw + (t * 16 + lc) * 64 + 32 + lg * 8), acc[t]);
            }
            #pragma unroll
            for (int t = 0; t < 4; ++t)
                #pragma unroll
                for (int j = 0; j < 4; ++j)
                    vnT[h2][t * 16 + lc][wid * 16 + lg * 4 + j] = f2b(acc[t][j]);
        }
        __syncthreads();

        // ---- prefetch next task (in flight through softmax/F/stores)
        f32x8 nk0 = {}, nk1 = {}, nv0 = {}, nv1 = {}, nq0 = {}, nq1 = {};
        int headN = 0, winN = 0, bN = 0;
        if (it + 1 < NT) {
            const int tn = task + 2;
            headN = tn % 12; winN = (tn / 12) & 63; bN = (tn / 12) >> 6;
            const long rbn = rbase(headN, winN, bN);
            nk0 = *reinterpret_cast<const f32x8*>(kf + rbn + lg * 8);
            nk1 = *reinterpret_cast<const f32x8*>(kf + rbn + 32 + lg * 8);
            nv0 = *reinterpret_cast<const f32x8*>(vf + rbn + lg * 8);
            nv1 = *reinterpret_cast<const f32x8*>(vf + rbn + 32 + lg * 8);
            nq0 = *reinterpret_cast<const f32x8*>(qf + rbn + lg * 8);
            nq1 = *reinterpret_cast<const f32x8*>(qf + rbn + 32 + lg * 8);
        }
        const int wy = winC >> 3, wx = winC & 7;

        // ---- S = qw * KM^T (/8 + bias + mask), softmax -> P (As)
        f32x4 accS[4] = {};
        {
            bf16x8 qa0 = cvtv(cq0), qa1 = cvtv(cq1);
            #pragma unroll
            for (int t = 0; t < 4; ++t) {
                accS[t] = MFMA16(qa0, ld8(&kmS[h2][t * 16 + lc][lg * 8]), accS[t]);
                accS[t] = MFMA16(qa1, ld8(&kmS[h2][t * 16 + lc][32 + lg * 8]), accS[t]);
            }
        }
        {
            float sv[4][4];
            #pragma unroll
            for (int t = 0; t < 4; ++t) {
                const int c = t * 16 + lc, ky = c >> 3, kx = c & 7;
                #pragma unroll
                for (int j = 0; j < 4; ++j) {
                    const int r = r0 + j, qy = r >> 3, qx = r & 7;
                    const float biasv = pe[(ky - qy + 7) * 15 + (kx - qx + 7)];
                    const bool msk = ((wy == 7) && (((qy ^ ky) & 4) != 0)) ||
                                     ((wx == 7) && (((qx ^ kx) & 4) != 0));
                    sv[t][j] = msk ? -__builtin_inff() : accS[t][j] * 0.125f + biasv;
                }
            }
            #pragma unroll
            for (int j = 0; j < 4; ++j) {
                float mx = fmaxf(fmaxf(sv[0][j], sv[1][j]), fmaxf(sv[2][j], sv[3][j]));
                mx = fmaxf(mx, __shfl_xor(mx, 1));
                mx = fmaxf(mx, __shfl_xor(mx, 2));
                mx = fmaxf(mx, __shfl_xor(mx, 4));
                mx = fmaxf(mx, __shfl_xor(mx, 8));   // row in one 16-lane group
                const float e0 = __expf(sv[0][j] - mx);
                const float e1 = __expf(sv[1][j] - mx);
                const float e2 = __expf(sv[2][j] - mx);
                const float e3 = __expf(sv[3][j] - mx);
                float sm = (e0 + e1) + (e2 + e3);
                sm += __shfl_xor(sm, 1);
                sm += __shfl_xor(sm, 2);
                sm += __shfl_xor(sm, 4);
                sm += __shfl_xor(sm, 8);
                const float inv = 1.0f / sm;
                As[h2][r0 + j][0 * 16 + lc] = f2b(e0 * inv);
                As[h2][r0 + j][1 * 16 + lc] = f2b(e1 * inv);
                As[h2][r0 + j][2 * 16 + lc] = f2b(e2 * inv);
                As[h2][r0 + j][3 * 16 + lc] = f2b(e3 * inv);
            }
        }

        // ---- attn dump (wave-local, full 64B lines)
        {
            const int lr = wid * 16 + (lane >> 2);
            const int c0 = (lane & 3) * 16;
            u16x8 p0 = *reinterpret_cast<const u16x8*>(&As[h2][lr][c0]);
            u16x8 p1 = *reinterpret_cast<const u16x8*>(&As[h2][lr][c0 + 8]);
            const long abase = ((((long)bC * 12 + headC) * 64 + winC) * 64 + lr) * 64 + c0;
            f32x4 o0, o1, o2, o3;
            #pragma unroll
            for (int i = 0; i < 4; ++i) { o0[i] = b2f(p0[i]); o1[i] = b2f(p0[4 + i]); }
            #pragma unroll
            for (int i = 0; i < 4; ++i) { o2[i] = b2f(p1[i]); o3[i] = b2f(p1[4 + i]); }
            *reinterpret_cast<f32x4*>(attn + abase)      = o0;
            *reinterpret_cast<f32x4*>(attn + abase + 4)  = o1;
            *reinterpret_cast<f32x4*>(attn + abase + 8)  = o2;
            *reinterpret_cast<f32x4*>(attn + abase + 12) = o3;
        }

        // ---- F = P * VN^T, direct fp32 scatter
        {
            bf16x8 a0 = ld8(&As[h2][srow][lg * 8]);
            bf16x8 a1 = ld8(&As[h2][srow][32 + lg * 8]);
            f32x4 acc[4] = {};
            #pragma unroll
            for (int t = 0; t < 4; ++t) {
                acc[t] = MFMA16(a0, ld8(&vnT[h2][t * 16 + lc][lg * 8]), acc[t]);
                acc[t] = MFMA16(a1, ld8(&vnT[h2][t * 16 + lc][32 + lg * 8]), acc[t]);
            }
            #pragma unroll
            for (int j = 0; j < 4; ++j) {
                const int r = r0 + j, ry = r >> 3, rx = r & 7;
                const int oy = (wy * 8 + ry + 4) & 63;
                const int ox = (wx * 8 + rx + 4) & 63;
                const long obase = ((long)bC * 4096 + oy * 64 + ox) * 768 + headC * 64;
                #pragma unroll
                for (int t = 0; t < 4; ++t)
                    out[obase + t * 16 + lc] = acc[t][j];
            }
        }

        __syncthreads();   // kmS/vnT reads done before next iter overwrites

        // ---- rotate pipeline registers
        ck0 = nk0; ck1 = nk1; cv0 = nv0; cv1 = nv1; cq0 = nq0; cq1 = nq1;
        headC = headN; winC = winN; bC = bN;
        task += 2;
    }
}

extern "C" void kernel_launch(void* const* d_in, const int* in_sizes, int n_in,
                              void* d_out, int out_size, void* d_ws, size_t ws_size,
                              hipStream_t stream) {
    const float* qf = (const float*)d_in[0];
    const float* kf = (const float*)d_in[1];
    const float* vf = (const float*)d_in[2];
    const float* Wq = (const float*)d_in[3];
    const float* Wk = (const float*)d_in[4];
    const float* Wv = (const float*)d_in[5];
    const float* Wl = (const float*)d_in[6];
    const float* pe = (const float*)d_in[7];

    const int B = in_sizes[0] / (4096 * 768);   // 8
    float* outp = (float*)d_out;
    float* attnp = outp + (size_t)B * 4096 * 768;
    unsigned short* ws = (unsigned short*)d_ws;

    precompute_mn<<<8, 256, 0, stream>>>(Wq, Wk, Wv, Wl, ws);

    const int nblk = B * 768 / (2 * NT);   // 512 persistent blocks (2/CU)
    swca_fused<<<nblk, 512, 0, stream>>>(qf, kf, vf, ws, ws + 4096, pe,
                                         outp, attnp);
}

// Round 12
// 132.185 us; speedup vs baseline: 1.8516x; 1.8516x over previous
//
#include <hip/hip_runtime.h>
#include <hip/hip_bf16.h>

typedef __bf16 bf16x8 __attribute__((ext_vector_type(8)));
typedef float f32x4 __attribute__((ext_vector_type(4)));
typedef float f32x8 __attribute__((ext_vector_type(8)));
typedef unsigned short u16x8 __attribute__((ext_vector_type(8)));

#define MFMA16(a, b, c) __builtin_amdgcn_mfma_f32_16x16x32_bf16((a), (b), (c), 0, 0, 0)

static __device__ __forceinline__ unsigned short f2b(float f) {
    union { float f; unsigned int u; } v; v.f = f;
    unsigned int r = v.u + 0x7FFFu + ((v.u >> 16) & 1u);  // RNE
    return (unsigned short)(r >> 16);
}
static __device__ __forceinline__ float b2f(unsigned short s) {
    union { unsigned int u; float f; } v; v.u = ((unsigned int)s) << 16;
    return v.f;
}
static __device__ __forceinline__ bf16x8 cvtv(f32x8 v) {
    bf16x8 r;
    #pragma unroll
    for (int i = 0; i < 8; ++i) r[i] = (__bf16)v[i];
    return r;
}

// ---------------- precompute (bf16, in d_ws) ----------------
// M[d][dp] = sum_e Wq[e][d] * Wk[e][dp]   (B-operand for KM = kw * M^T)
// N[e][d]  = sum_c Wl[e][c] * Wv[c][d]    (B-operand for VN = vw * N^T)
__global__ __launch_bounds__(256) void precompute_mn(
    const float* __restrict__ Wq, const float* __restrict__ Wk,
    const float* __restrict__ Wv, const float* __restrict__ Wl,
    unsigned short* __restrict__ ws)
{
    __shared__ float A[4096], B[4096];
    const int bid = blockIdx.x;          // 8 blocks
    const int which = bid >> 2;          // 0 = M, 1 = N
    const int rq = bid & 3;              // row quad
    const int tid = threadIdx.x;
    for (int i = tid; i < 4096; i += 256) {
        A[i] = which ? Wl[i] : Wq[i];
        B[i] = which ? Wv[i] : Wk[i];
    }
    __syncthreads();
    const int row = rq * 16 + (tid >> 4);
    const int c0  = tid & 15;
    float acc[4] = {0, 0, 0, 0};
    if (which == 0) {        // M[row][col] = sum_e Wq[e][row] * Wk[e][col]
        for (int e = 0; e < 64; ++e) {
            const float s = A[e * 64 + row];
            #pragma unroll
            for (int i = 0; i < 4; ++i) acc[i] += s * B[e * 64 + c0 + 16 * i];
        }
    } else {                 // N[row][col] = sum_c Wl[row][c] * Wv[c][col]
        for (int c = 0; c < 64; ++c) {
            const float s = A[row * 64 + c];
            #pragma unroll
            for (int i = 0; i < 4; ++i) acc[i] += s * B[c * 64 + c0 + 16 * i];
        }
    }
    #pragma unroll
    for (int i = 0; i < 4; ++i)
        ws[which * 4096 + row * 64 + c0 + 16 * i] = f2b(acc[i]);
}

#define PITCH 68
#define NT 6

// Persistent pipelined kernel: 1024 blocks x 256 threads (4 waves, ONE task
// stream). Block g runs tasks [g*6, g*6+6) — consecutive heads of one window
// (max L1/L2 row reuse). Carried state is bf16 (24 VGPR); the six f32x8
// prefetch loads are issued right after barrier #1 and land during softmax/
// F/stores; converted to bf16 after barrier #2. NO launch-bounds occupancy
// arg (R7/R11: any 2nd arg -> 64-VGPR clamp -> spill).
// Chain per task: KM = kw*M^T, VN = vw*N^T -> barrier -> S = qw*KM^T
// (/8+bias+mask, softmax) -> attn -> F = P*VN^T -> out -> barrier.
// mfma 16x16x32 bf16: a/b-frag lane l holds row/col (l&15), k=(l>>4)*8+i;
// D: col=lane&15, row=(lane>>4)*4+reg.
__global__ __launch_bounds__(256) void swca_fused(
    const float* __restrict__ qf,
    const float* __restrict__ kf,
    const float* __restrict__ vf,
    const unsigned short* __restrict__ Mw,   // ws
    const unsigned short* __restrict__ Nw,   // ws + 4096
    const float* __restrict__ pe,
    float* __restrict__ out,
    float* __restrict__ attn)
{
    __shared__ unsigned short kmS[64][PITCH];  // KM = kw*M^T  [k][d]
    __shared__ unsigned short vnT[64][PITCH];  // VN^T         [e][k]
    __shared__ unsigned short As[64][PITCH];   // P (wave-private bands)

    const int bid = blockIdx.x;
    const int g = (bid & 7) * 128 + (bid >> 3);  // XCD-chunked swizzle (1024 blocks)

    const int tid  = threadIdx.x;
    const int wid  = tid >> 6;
    const int lane = tid & 63;
    const int lg   = lane >> 4;   // k-group 0..3
    const int lc   = lane & 15;   // row/col within 16-tile
    const int srow = wid * 16 + lc;
    const int sy = srow >> 3, sx = srow & 7;
    const int r0 = wid * 16 + lg * 4;

    auto ld8 = [](const unsigned short* p) -> bf16x8 {
        return *reinterpret_cast<const bf16x8*>(p);
    };
    auto rbase = [&](int hd, int wn, int bb) -> long {
        const int wy = wn >> 3, wx = wn & 7;
        const int gy = (wy * 8 + sy + 4) & 63;   // +4 roll gather
        const int gx = (wx * 8 + sx + 4) & 63;
        return ((long)bb * 4096 + gy * 64 + gx) * 768 + hd * 64;
    };

    int task = g * NT;
    int headC = task % 12;
    int winC  = (task / 12) & 63;
    int bC    = (task / 12) >> 6;

    // prologue: task-0 loads, converted immediately (one-time stall)
    bf16x8 kb0, kb1, vb0, vb1, qa0, qa1;
    {
        const long rb = rbase(headC, winC, bC);
        kb0 = cvtv(*reinterpret_cast<const f32x8*>(kf + rb + lg * 8));
        kb1 = cvtv(*reinterpret_cast<const f32x8*>(kf + rb + 32 + lg * 8));
        vb0 = cvtv(*reinterpret_cast<const f32x8*>(vf + rb + lg * 8));
        vb1 = cvtv(*reinterpret_cast<const f32x8*>(vf + rb + 32 + lg * 8));
        qa0 = cvtv(*reinterpret_cast<const f32x8*>(qf + rb + lg * 8));
        qa1 = cvtv(*reinterpret_cast<const f32x8*>(qf + rb + 32 + lg * 8));
    }

    for (int it = 0; it < NT; ++it) {
        // ---- KM = kw*M^T, VN = vw*N^T (consume carried bf16 regs)
        {
            f32x4 acc[4] = {};
            #pragma unroll
            for (int t = 0; t < 4; ++t) {
                acc[t] = MFMA16(kb0, ld8(Mw + (t * 16 + lc) * 64 + lg * 8), acc[t]);
                acc[t] = MFMA16(kb1, ld8(Mw + (t * 16 + lc) * 64 + 32 + lg * 8), acc[t]);
            }
            #pragma unroll
            for (int t = 0; t < 4; ++t)
                #pragma unroll
                for (int j = 0; j < 4; ++j)
                    kmS[wid * 16 + lg * 4 + j][t * 16 + lc] = f2b(acc[t][j]);
        }
        {
            f32x4 acc[4] = {};
            #pragma unroll
            for (int t = 0; t < 4; ++t) {
                acc[t] = MFMA16(vb0, ld8(Nw + (t * 16 + lc) * 64 + lg * 8), acc[t]);
                acc[t] = MFMA16(vb1, ld8(Nw + (t * 16 + lc) * 64 + 32 + lg * 8), acc[t]);
            }
            #pragma unroll
            for (int t = 0; t < 4; ++t)
                #pragma unroll
                for (int j = 0; j < 4; ++j)
                    vnT[t * 16 + lc][wid * 16 + lg * 4 + j] = f2b(acc[t][j]);
        }
        __syncthreads();

        // ---- issue next task's loads (fly through softmax/F/stores)
        f32x8 nk0 = {}, nk1 = {}, nv0 = {}, nv1 = {}, nq0 = {}, nq1 = {};
        int headN = 0, winN = 0, bN = 0;
        if (it + 1 < NT) {
            const int tn = task + 1;
            headN = tn % 12; winN = (tn / 12) & 63; bN = (tn / 12) >> 6;
            const long rbn = rbase(headN, winN, bN);
            nk0 = *reinterpret_cast<const f32x8*>(kf + rbn + lg * 8);
            nk1 = *reinterpret_cast<const f32x8*>(kf + rbn + 32 + lg * 8);
            nv0 = *reinterpret_cast<const f32x8*>(vf + rbn + lg * 8);
            nv1 = *reinterpret_cast<const f32x8*>(vf + rbn + 32 + lg * 8);
            nq0 = *reinterpret_cast<const f32x8*>(qf + rbn + lg * 8);
            nq1 = *reinterpret_cast<const f32x8*>(qf + rbn + 32 + lg * 8);
        }
        const int wy = winC >> 3, wx = winC & 7;

        // ---- S = qw * KM^T (/8 + bias + mask), softmax -> P (As)
        f32x4 accS[4] = {};
        {
            #pragma unroll
            for (int t = 0; t < 4; ++t) {
                accS[t] = MFMA16(qa0, ld8(&kmS[t * 16 + lc][lg * 8]), accS[t]);
                accS[t] = MFMA16(qa1, ld8(&kmS[t * 16 + lc][32 + lg * 8]), accS[t]);
            }
        }
        {
            float sv[4][4];
            #pragma unroll
            for (int t = 0; t < 4; ++t) {
                const int c = t * 16 + lc, ky = c >> 3, kx = c & 7;
                #pragma unroll
                for (int j = 0; j < 4; ++j) {
                    const int r = r0 + j, qy = r >> 3, qx = r & 7;
                    const float biasv = pe[(ky - qy + 7) * 15 + (kx - qx + 7)];
                    const bool msk = ((wy == 7) && (((qy ^ ky) & 4) != 0)) ||
                                     ((wx == 7) && (((qx ^ kx) & 4) != 0));
                    sv[t][j] = msk ? -__builtin_inff() : accS[t][j] * 0.125f + biasv;
                }
            }
            #pragma unroll
            for (int j = 0; j < 4; ++j) {
                float mx = fmaxf(fmaxf(sv[0][j], sv[1][j]), fmaxf(sv[2][j], sv[3][j]));
                mx = fmaxf(mx, __shfl_xor(mx, 1));
                mx = fmaxf(mx, __shfl_xor(mx, 2));
                mx = fmaxf(mx, __shfl_xor(mx, 4));
                mx = fmaxf(mx, __shfl_xor(mx, 8));   // row in one 16-lane group
                const float e0 = __expf(sv[0][j] - mx);
                const float e1 = __expf(sv[1][j] - mx);
                const float e2 = __expf(sv[2][j] - mx);
                const float e3 = __expf(sv[3][j] - mx);
                float sm = (e0 + e1) + (e2 + e3);
                sm += __shfl_xor(sm, 1);
                sm += __shfl_xor(sm, 2);
                sm += __shfl_xor(sm, 4);
                sm += __shfl_xor(sm, 8);
                const float inv = 1.0f / sm;
                As[r0 + j][0 * 16 + lc] = f2b(e0 * inv);
                As[r0 + j][1 * 16 + lc] = f2b(e1 * inv);
                As[r0 + j][2 * 16 + lc] = f2b(e2 * inv);
                As[r0 + j][3 * 16 + lc] = f2b(e3 * inv);
            }
        }

        // ---- attn dump (wave-local, full 64B lines)
        {
            const int lr = wid * 16 + (lane >> 2);
            const int c0 = (lane & 3) * 16;
            u16x8 p0 = *reinterpret_cast<const u16x8*>(&As[lr][c0]);
            u16x8 p1 = *reinterpret_cast<const u16x8*>(&As[lr][c0 + 8]);
            const long abase = ((((long)bC * 12 + headC) * 64 + winC) * 64 + lr) * 64 + c0;
            f32x4 o0, o1, o2, o3;
            #pragma unroll
            for (int i = 0; i < 4; ++i) { o0[i] = b2f(p0[i]); o1[i] = b2f(p0[4 + i]); }
            #pragma unroll
            for (int i = 0; i < 4; ++i) { o2[i] = b2f(p1[i]); o3[i] = b2f(p1[4 + i]); }
            *reinterpret_cast<f32x4*>(attn + abase)      = o0;
            *reinterpret_cast<f32x4*>(attn + abase + 4)  = o1;
            *reinterpret_cast<f32x4*>(attn + abase + 8)  = o2;
            *reinterpret_cast<f32x4*>(attn + abase + 12) = o3;
        }

        // ---- F = P * VN^T, direct fp32 scatter
        {
            bf16x8 a0 = ld8(&As[srow][lg * 8]);
            bf16x8 a1 = ld8(&As[srow][32 + lg * 8]);
            f32x4 acc[4] = {};
            #pragma unroll
            for (int t = 0; t < 4; ++t) {
                acc[t] = MFMA16(a0, ld8(&vnT[t * 16 + lc][lg * 8]), acc[t]);
                acc[t] = MFMA16(a1, ld8(&vnT[t * 16 + lc][32 + lg * 8]), acc[t]);
            }
            #pragma unroll
            for (int j = 0; j < 4; ++j) {
                const int r = r0 + j, ry = r >> 3, rx = r & 7;
                const int oy = (wy * 8 + ry + 4) & 63;
                const int ox = (wx * 8 + rx + 4) & 63;
                const long obase = ((long)bC * 4096 + oy * 64 + ox) * 768 + headC * 64;
                #pragma unroll
                for (int t = 0; t < 4; ++t)
                    out[obase + t * 16 + lc] = acc[t][j];
            }
        }

        __syncthreads();   // kmS/vnT reads done; prefetch loads drained here too

        // ---- convert landed prefetch to carried bf16, rotate ids
        if (it + 1 < NT) {
            kb0 = cvtv(nk0); kb1 = cvtv(nk1);
            vb0 = cvtv(nv0); vb1 = cvtv(nv1);
            qa0 = cvtv(nq0); qa1 = cvtv(nq1);
            headC = headN; winC = winN; bC = bN;
            ++task;
        }
    }
}

extern "C" void kernel_launch(void* const* d_in, const int* in_sizes, int n_in,
                              void* d_out, int out_size, void* d_ws, size_t ws_size,
                              hipStream_t stream) {
    const float* qf = (const float*)d_in[0];
    const float* kf = (const float*)d_in[1];
    const float* vf = (const float*)d_in[2];
    const float* Wq = (const float*)d_in[3];
    const float* Wk = (const float*)d_in[4];
    const float* Wv = (const float*)d_in[5];
    const float* Wl = (const float*)d_in[6];
    const float* pe = (const float*)d_in[7];

    const int B = in_sizes[0] / (4096 * 768);   // 8
    float* outp = (float*)d_out;
    float* attnp = outp + (size_t)B * 4096 * 768;
    unsigned short* ws = (unsigned short*)d_ws;

    precompute_mn<<<8, 256, 0, stream>>>(Wq, Wk, Wv, Wl, ws);

    const int nblk = B * 768 / NT;   // 1024 persistent blocks
    swca_fused<<<nblk, 256, 0, stream>>>(qf, kf, vf, ws, ws + 4096, pe,
                                         outp, attnp);
}